// Round 6
// baseline (524.360 us; speedup 1.0000x reference)
//
#include <hip/hip_runtime.h>
#include <hip/hip_bf16.h>

#define N_NODES 10000
#define N_EDGES 160000
#define DD      256   // hidden dim

typedef __bf16 bf16x8 __attribute__((ext_vector_type(8)));
typedef float  f32x4  __attribute__((ext_vector_type(4)));

// ---------------------------------------------------------------------------
// W[K,256] f32 -> Wt[256,K] bf16 (transpose + convert)
// ---------------------------------------------------------------------------
__global__ void wtrans_kernel(const float* __restrict__ W,
                              __hip_bfloat16* __restrict__ Wt, int K) {
  const int idx = blockIdx.x * 256 + threadIdx.x;  // n*K + k
  if (idx >= 256 * K) return;
  const int n = idx / K, k = idx % K;
  Wt[idx] = __float2bfloat16(W[k * 256 + n]);
}

// ---------------------------------------------------------------------------
// Edge-side fused weight We'[768 n][256 k]: the pre_e rows of Wpa/Wsa/Wet.
// n: [0,256)->msg_p, [256,512)->msg_s, [512,768)->edge_out.
// ---------------------------------------------------------------------------
__global__ void build_we_kernel(const float* __restrict__ Wpa,
                                const float* __restrict__ Wsa,
                                const float* __restrict__ Wet,
                                __hip_bfloat16* __restrict__ Wt) {
  const int idx = blockIdx.x * 256 + threadIdx.x;  // n*256 + k
  if (idx >= 768 * 256) return;
  const int n = idx >> 8, k = idx & 255;
  float v;
  if (n < 256)      v = Wpa[(256 + k) * 256 + n];
  else if (n < 512) v = Wsa[(256 + k) * 256 + (n - 256)];
  else              v = Wet[(256 + k) * 256 + (n - 512)];
  Wt[idx] = __float2bfloat16(v);
}

// ---------------------------------------------------------------------------
// Node-side fused weight Wn'[1024 n][256 k]:
// n: [0,256)=Wpa top (Pp, gathered by src), [256,512)=Wsa top (Ps, by dst),
//    [512,768)=Wet top (Qs, by src), [768,1024)=Wet bottom (Qd, by dst).
// ---------------------------------------------------------------------------
__global__ void build_wn_kernel(const float* __restrict__ Wpa,
                                const float* __restrict__ Wsa,
                                const float* __restrict__ Wet,
                                __hip_bfloat16* __restrict__ Wt) {
  const int idx = blockIdx.x * 256 + threadIdx.x;  // n*256 + k
  if (idx >= 1024 * 256) return;
  const int n = idx >> 8, k = idx & 255;
  float v;
  if (n < 256)      v = Wpa[k * 256 + n];
  else if (n < 512) v = Wsa[k * 256 + (n - 256)];
  else if (n < 768) v = Wet[k * 256 + (n - 512)];
  else              v = Wet[(512 + k) * 256 + (n - 768)];
  Wt[idx] = __float2bfloat16(v);
}

// ---------------------------------------------------------------------------
// CSR build: counts, exclusive scan, inverse-permutation fill
// ---------------------------------------------------------------------------
__global__ void count_kernel(const int* __restrict__ src, const int* __restrict__ dst,
                             int* __restrict__ cnt_out, int* __restrict__ cnt_in) {
  const int e = blockIdx.x * 256 + threadIdx.x;
  if (e < N_EDGES) {
    atomicAdd(&cnt_out[src[e]], 1);
    atomicAdd(&cnt_in[dst[e]], 1);
  }
}

__global__ __launch_bounds__(256) void scan_kernel(const int* __restrict__ cnt,
                                                   int* __restrict__ offs, int n) {
  __shared__ int part[256];
  const int t  = threadIdx.x;
  const int lo = t * 40;
  const int hi = (lo + 40 < n) ? lo + 40 : n;
  int s = 0;
  for (int i = lo; i < hi; ++i) s += cnt[i];
  part[t] = s;
  __syncthreads();
  for (int off = 1; off < 256; off <<= 1) {
    int v = (t >= off) ? part[t - off] : 0;
    __syncthreads();
    part[t] += v;
    __syncthreads();
  }
  int run = (t == 0) ? 0 : part[t - 1];
  for (int i = lo; i < hi; ++i) { offs[i] = run; run += cnt[i]; }
  if (t == 255) offs[n] = run;
}

__global__ void fill_kernel(const int* __restrict__ src, const int* __restrict__ dst,
                            const int* __restrict__ offs_out, const int* __restrict__ offs_in,
                            int* __restrict__ cur_out, int* __restrict__ cur_in,
                            int* __restrict__ pos_out, int* __restrict__ pos_in) {
  const int e = blockIdx.x * 256 + threadIdx.x;
  if (e < N_EDGES) {
    const int u = src[e];
    pos_out[e] = offs_out[u] + atomicAdd(&cur_out[u], 1);
    const int v = dst[e];
    pos_in[e] = offs_in[v] + atomicAdd(&cur_in[v], 1);
  }
}

// ---------------------------------------------------------------------------
// Generic MFMA GEMM (m97 structure): out[M,ldo] cols [nt*128..) =
//   act(A[M,K] @ Wt^T + bias). A_F32: f32 A converted during reg-staged write.
// ---------------------------------------------------------------------------
template <bool RELU, bool F32OUT, bool A_F32>
__global__ __launch_bounds__(256, 2) void gemm_mfma_kernel(
    const void* __restrict__ Av, const __hip_bfloat16* __restrict__ Wt,
    const float* __restrict__ bias, float* __restrict__ outf,
    __hip_bfloat16* __restrict__ outb, int M, int Ksteps, int ldo) {
  __shared__ char sA[2][16384];
  __shared__ char sW[2][16384];

  const int K    = Ksteps * 64;
  const int row0 = blockIdx.x * 128;
  const int nt   = blockIdx.y;

  const int tid  = threadIdx.x;
  const int lane = tid & 63;
  const int w    = tid >> 6;

  const int rsub  = lane >> 3;
  const int pslot = lane & 7;
  const int sslot = pslot ^ rsub;

  auto stage = [&](int b, int c) {
#pragma unroll
    for (int j = 0; j < 4; ++j) {
      const int r = w * 32 + j * 8 + rsub;
      int ar = row0 + r;
      if (ar >= M) ar = M - 1;
      if constexpr (A_F32) {
        const float* gp = (const float*)Av + (size_t)ar * K + c * 64 + sslot * 8;
        const f32x4 lo = *(const f32x4*)gp;
        const f32x4 hi = *(const f32x4*)(gp + 4);
        union { __hip_bfloat16 h[8]; bf16x8 v; } pk;
#pragma unroll
        for (int q = 0; q < 4; ++q) pk.h[q] = __float2bfloat16(lo[q]);
#pragma unroll
        for (int q = 0; q < 4; ++q) pk.h[4 + q] = __float2bfloat16(hi[q]);
        *(bf16x8*)&sA[b][r * 128 + pslot * 16] = pk.v;
      } else {
        const __hip_bfloat16* gp =
            (const __hip_bfloat16*)Av + (size_t)ar * K + c * 64 + sslot * 8;
        __builtin_amdgcn_global_load_lds(
            (const __attribute__((address_space(1))) void*)gp,
            (__attribute__((address_space(3))) void*)&sA[b][(w * 32 + j * 8) * 128],
            16, 0, 0);
      }
      const __hip_bfloat16* wp = Wt + (size_t)(nt * 128 + r) * K + c * 64 + sslot * 8;
      __builtin_amdgcn_global_load_lds(
          (const __attribute__((address_space(1))) void*)wp,
          (__attribute__((address_space(3))) void*)&sW[b][(w * 32 + j * 8) * 128],
          16, 0, 0);
    }
  };

  const int wm = (w >> 1) * 64;
  const int wn = (w & 1) * 64;

  f32x4 acc[4][4];
#pragma unroll
  for (int i = 0; i < 4; ++i)
#pragma unroll
    for (int j = 0; j < 4; ++j) acc[i][j] = (f32x4)0.f;

  stage(0, 0);
  asm volatile("s_waitcnt vmcnt(0)");
  __syncthreads();

  int buf = 0;
  for (int c = 0; c < Ksteps; ++c) {
    if (c + 1 < Ksteps) stage(buf ^ 1, c + 1);
#pragma unroll
    for (int kk = 0; kk < 2; ++kk) {
      bf16x8 av[4], bv[4];
#pragma unroll
      for (int i = 0; i < 4; ++i) {
        const int row  = wm + i * 16 + (lane & 15);
        const int boff = row * 128 + ((kk * 64 + (lane >> 4) * 16) ^ ((row & 7) << 4));
        av[i] = *(const bf16x8*)&sA[buf][boff];
      }
#pragma unroll
      for (int j = 0; j < 4; ++j) {
        const int nrow = wn + j * 16 + (lane & 15);
        const int boff = nrow * 128 + ((kk * 64 + (lane >> 4) * 16) ^ ((nrow & 7) << 4));
        bv[j] = *(const bf16x8*)&sW[buf][boff];
      }
#pragma unroll
      for (int i = 0; i < 4; ++i)
#pragma unroll
        for (int j = 0; j < 4; ++j)
          acc[i][j] = __builtin_amdgcn_mfma_f32_16x16x32_bf16(av[i], bv[j], acc[i][j], 0, 0, 0);
    }
    __syncthreads();
    buf ^= 1;
  }

#pragma unroll
  for (int i = 0; i < 4; ++i) {
    const int row = row0 + wm + i * 16 + ((lane >> 4) << 2);
#pragma unroll
    for (int j = 0; j < 4; ++j) {
      const int col = nt * 128 + wn + j * 16 + (lane & 15);
      const float bb = bias ? bias[col] : 0.f;
#pragma unroll
      for (int r = 0; r < 4; ++r) {
        if (row + r < M) {
          float v = acc[i][j][r] + bb;
          if (RELU) v = v > 0.f ? v : 0.f;
          if (F32OUT) outf[(size_t)(row + r) * ldo + col] = v;
          else        outb[(size_t)(row + r) * ldo + col] = __float2bfloat16(v);
        }
      }
    }
  }
}

// ---------------------------------------------------------------------------
// Factored MFMA edge GEMM: acc = pre_e[128 edges] @ We'[768,256]^T (K=256).
// Epilogue adds gathered nodeP rows (bf16, L2/L3-resident), bias, relu, and
// scatters msg rows in CSR order (MSG) or atomicAdds (fallback).
// nodeP cols: [0,256)=Pp(src), [256,512)=Ps(dst), [512,768)=Qs(src), [768,1024)=Qd(dst).
// XCD-grouped remap: 6 nt-blocks of an edge-tile share an XCD.
// ---------------------------------------------------------------------------
template <bool MSG>
__global__ __launch_bounds__(256, 2) void edge_mfma_kernel(
    const __hip_bfloat16* __restrict__ pre_e,
    const __hip_bfloat16* __restrict__ We,
    const __hip_bfloat16* __restrict__ nodeP,
    const int* __restrict__ src, const int* __restrict__ dst,
    const int* __restrict__ pos_in, const int* __restrict__ pos_out,
    const float* __restrict__ bpa, const float* __restrict__ bsa,
    const float* __restrict__ bet,
    float* __restrict__ agg_p, float* __restrict__ agg_s,
    __hip_bfloat16* __restrict__ msg_p, __hip_bfloat16* __restrict__ msg_s,
    float* __restrict__ edge_out) {
  __shared__ char sA[2][16384];
  __shared__ char sW[2][16384];
  __shared__ int sSrc[128], sDst[128], sPin[128], sPout[128];

  const int bid = blockIdx.x;
  const int xcd = bid & 7;
  const int s   = xcd * 938 + (bid >> 3);
  const int et  = s / 6;
  const int nt  = s % 6;
  if (et >= N_EDGES / 128) return;
  const int mat = nt >> 1;  // 0=P, 1=S, 2=E
  const int e0  = et * 128;

  const int tid  = threadIdx.x;
  const int lane = tid & 63;
  const int w    = tid >> 6;

  if (tid < 128) {
    sSrc[tid] = src[e0 + tid];
    if (MSG) sPin[tid] = pos_in[e0 + tid];
  } else {
    sDst[tid - 128] = dst[e0 + tid - 128];
    if (MSG) sPout[tid - 128] = pos_out[e0 + tid - 128];
  }
  __syncthreads();

  const int rsub  = lane >> 3;
  const int pslot = lane & 7;
  const int sslot = pslot ^ rsub;

  auto stage = [&](int b, int c) {
#pragma unroll
    for (int j = 0; j < 4; ++j) {
      const int r = w * 32 + j * 8 + rsub;
      const __hip_bfloat16* gp = pre_e + (size_t)(e0 + r) * 256 + c * 64 + sslot * 8;
      __builtin_amdgcn_global_load_lds(
          (const __attribute__((address_space(1))) void*)gp,
          (__attribute__((address_space(3))) void*)&sA[b][(w * 32 + j * 8) * 128],
          16, 0, 0);
      const __hip_bfloat16* wp = We + (size_t)(nt * 128 + r) * 256 + c * 64 + sslot * 8;
      __builtin_amdgcn_global_load_lds(
          (const __attribute__((address_space(1))) void*)wp,
          (__attribute__((address_space(3))) void*)&sW[b][(w * 32 + j * 8) * 128],
          16, 0, 0);
    }
  };

  const int wm = (w >> 1) * 64;
  const int wn = (w & 1) * 64;

  f32x4 acc[4][4];
#pragma unroll
  for (int i = 0; i < 4; ++i)
#pragma unroll
    for (int j = 0; j < 4; ++j) acc[i][j] = (f32x4)0.f;

  stage(0, 0);
  asm volatile("s_waitcnt vmcnt(0)");
  __syncthreads();

  int buf = 0;
  for (int c = 0; c < 4; ++c) {
    if (c + 1 < 4) stage(buf ^ 1, c + 1);
#pragma unroll
    for (int kk = 0; kk < 2; ++kk) {
      bf16x8 av[4], bv[4];
#pragma unroll
      for (int i = 0; i < 4; ++i) {
        const int row  = wm + i * 16 + (lane & 15);
        const int boff = row * 128 + ((kk * 64 + (lane >> 4) * 16) ^ ((row & 7) << 4));
        av[i] = *(const bf16x8*)&sA[buf][boff];
      }
#pragma unroll
      for (int j = 0; j < 4; ++j) {
        const int nrow = wn + j * 16 + (lane & 15);
        const int boff = nrow * 128 + ((kk * 64 + (lane >> 4) * 16) ^ ((nrow & 7) << 4));
        bv[j] = *(const bf16x8*)&sW[buf][boff];
      }
#pragma unroll
      for (int i = 0; i < 4; ++i)
#pragma unroll
        for (int j = 0; j < 4; ++j)
          acc[i][j] = __builtin_amdgcn_mfma_f32_16x16x32_bf16(av[i], bv[j], acc[i][j], 0, 0, 0);
    }
    __syncthreads();
    buf ^= 1;
  }

  const int colbase = (nt & 1) * 128 + wn;
#pragma unroll
  for (int i = 0; i < 4; ++i) {
    const int lrow = wm + i * 16 + ((lane >> 4) << 2);  // 0..127 within tile
#pragma unroll
    for (int j = 0; j < 4; ++j) {
      const int col = colbase + j * 16 + (lane & 15);  // col within this mat's 256
      if (mat == 0) {
        const float bb = bpa[col];
#pragma unroll
        for (int r = 0; r < 4; ++r) {
          const int le = lrow + r;
          float v = acc[i][j][r] + bb +
                    __bfloat162float(nodeP[(size_t)sSrc[le] * 1024 + col]);
          v = v > 0.f ? v : 0.f;
          if (MSG) msg_p[(size_t)sPin[le] * 256 + col] = __float2bfloat16(v);
          else     atomicAdd(&agg_p[(size_t)sDst[le] * 256 + col], v);
        }
      } else if (mat == 1) {
        const float bb = bsa[col];
#pragma unroll
        for (int r = 0; r < 4; ++r) {
          const int le = lrow + r;
          float v = acc[i][j][r] + bb +
                    __bfloat162float(nodeP[(size_t)sDst[le] * 1024 + 256 + col]);
          v = v > 0.f ? v : 0.f;
          if (MSG) msg_s[(size_t)sPout[le] * 256 + col] = __float2bfloat16(v);
          else     atomicAdd(&agg_s[(size_t)sSrc[le] * 256 + col], v);
        }
      } else {
        const float bb = bet[col];
#pragma unroll
        for (int r = 0; r < 4; ++r) {
          const int le = lrow + r;
          float v = acc[i][j][r] + bb +
                    __bfloat162float(nodeP[(size_t)sSrc[le] * 1024 + 512 + col]) +
                    __bfloat162float(nodeP[(size_t)sDst[le] * 1024 + 768 + col]);
          edge_out[(size_t)(e0 + le) * 256 + col] = v;
        }
      }
    }
  }
}

// ---------------------------------------------------------------------------
// CSR-ordered segment-sum + nodeH assembly. msg rows are contiguous per node.
// Block = 1 node, 128 threads: wave 0 -> P (in), wave 1 -> S (out).
// ---------------------------------------------------------------------------
__global__ __launch_bounds__(128) void agg_kernel(
    const __hip_bfloat16* __restrict__ msg_p, const __hip_bfloat16* __restrict__ msg_s,
    const __hip_bfloat16* __restrict__ pre_n,
    const int* __restrict__ offs_in, const int* __restrict__ offs_out,
    __hip_bfloat16* __restrict__ nodeH) {
  const int v    = blockIdx.x;
  const int wave = threadIdx.x >> 6;
  const int lane = threadIdx.x & 63;
  const int cg   = lane & 31;   // col group: cols cg*8..cg*8+7
  const int par  = lane >> 5;   // row parity

  const int* offs = wave ? offs_out : offs_in;
  const __hip_bfloat16* msg = wave ? msg_s : msg_p;

  const int p0 = offs[v], p1 = offs[v + 1];
  float acc[8];
#pragma unroll
  for (int k = 0; k < 8; ++k) acc[k] = 0.f;

  for (int i = p0 + par; i < p1; i += 2) {
    const uint4 u = *(const uint4*)(msg + (size_t)i * 256 + cg * 8);
    const unsigned short* h = (const unsigned short*)&u;
#pragma unroll
    for (int k = 0; k < 8; ++k) acc[k] += __uint_as_float((unsigned)h[k] << 16);
  }
#pragma unroll
  for (int k = 0; k < 8; ++k) acc[k] += __shfl_xor(acc[k], 32);

  if (par == 0) {
    const int deg = p1 - p0;
    const float inv = 1.f / (float)(deg > 1 ? deg : 1);
    union { __hip_bfloat16 h[8]; uint4 u; } o;
#pragma unroll
    for (int k = 0; k < 8; ++k) o.h[k] = __float2bfloat16(acc[k] * inv);
    *(uint4*)(nodeH + (size_t)v * 768 + wave * 512 + cg * 8) = o.u;
  } else if (wave == 0) {
    const uint4 u = *(const uint4*)(pre_n + (size_t)v * 256 + cg * 8);
    *(uint4*)(nodeH + (size_t)v * 768 + 256 + cg * 8) = u;
  }
}

// ---------------------------------------------------------------------------
// fallback node prep (atomic path)
// ---------------------------------------------------------------------------
__global__ void node_prep_kernel(const float* __restrict__ agg_p,
                                 const float* __restrict__ agg_s,
                                 const __hip_bfloat16* __restrict__ pre_n,
                                 const int* __restrict__ cnt_in,
                                 const int* __restrict__ cnt_out,
                                 __hip_bfloat16* __restrict__ nodeH) {
  const int row = blockIdx.x;
  const int c   = threadIdx.x;
  const float di = (float)(cnt_in[row]  > 1 ? cnt_in[row]  : 1);
  const float dd = (float)(cnt_out[row] > 1 ? cnt_out[row] : 1);
  nodeH[(size_t)row * 768 + c]       = __float2bfloat16(agg_p[(size_t)row * 256 + c] / di);
  nodeH[(size_t)row * 768 + 256 + c] = pre_n[(size_t)row * 256 + c];
  nodeH[(size_t)row * 768 + 512 + c] = __float2bfloat16(agg_s[(size_t)row * 256 + c] / dd);
}

// ---------------------------------------------------------------------------
extern "C" void kernel_launch(void* const* d_in, const int* in_sizes, int n_in,
                              void* d_out, int out_size, void* d_ws, size_t ws_size,
                              hipStream_t stream) {
  const float* x         = (const float*)d_in[0];
  const float* edge_feat = (const float*)d_in[1];
  const int*   edge_idx  = (const int*)d_in[2];
  const float* Wn  = (const float*)d_in[3];
  const float* bn  = (const float*)d_in[4];
  const float* We  = (const float*)d_in[5];
  const float* be  = (const float*)d_in[6];
  const float* Wpa = (const float*)d_in[7];
  const float* bpa = (const float*)d_in[8];
  const float* Wsa = (const float*)d_in[9];
  const float* bsa = (const float*)d_in[10];
  const float* Wnt = (const float*)d_in[11];
  const float* bnt = (const float*)d_in[12];
  const float* Wet = (const float*)d_in[13];
  const float* bet = (const float*)d_in[14];

  const int* src = edge_idx;
  const int* dst = edge_idx + N_EDGES;

  float* node_out = (float*)d_out;
  float* edge_out = (float*)d_out + (size_t)N_NODES * DD;

  char* p = (char*)d_ws;
  auto alloc = [&](size_t bytes) -> void* {
    void* r = (void*)p;
    p += (bytes + 255) & ~(size_t)255;
    return r;
  };

  __hip_bfloat16* pre_n_bf = (__hip_bfloat16*)alloc((size_t)N_NODES * DD * 2);
  __hip_bfloat16* pre_e_bf = (__hip_bfloat16*)alloc((size_t)N_EDGES * DD * 2);
  __hip_bfloat16* nodeH    = (__hip_bfloat16*)alloc((size_t)N_NODES * 768 * 2);
  __hip_bfloat16* nodeP    = (__hip_bfloat16*)alloc((size_t)N_NODES * 1024 * 2);
  __hip_bfloat16* We_edge  = (__hip_bfloat16*)alloc((size_t)768 * 256 * 2);
  __hip_bfloat16* Wn_node  = (__hip_bfloat16*)alloc((size_t)1024 * 256 * 2);
  __hip_bfloat16* Wn_t     = (__hip_bfloat16*)alloc((size_t)256 * 256 * 2);
  __hip_bfloat16* We_t     = (__hip_bfloat16*)alloc((size_t)256 * 128 * 2);
  __hip_bfloat16* Wnt_t    = (__hip_bfloat16*)alloc((size_t)256 * 768 * 2);
  int* csr_zero = (int*)alloc(4 * (size_t)N_NODES * 4);  // cnt_in|cnt_out|cur_in|cur_out
  int* cnt_in   = csr_zero;
  int* cnt_out  = csr_zero + N_NODES;
  int* cur_in   = csr_zero + 2 * N_NODES;
  int* cur_out  = csr_zero + 3 * N_NODES;
  int* offs_in  = (int*)alloc(((size_t)N_NODES + 1) * 4);
  int* offs_out = (int*)alloc(((size_t)N_NODES + 1) * 4);
  int* pos_in   = (int*)alloc((size_t)N_EDGES * 4);
  int* pos_out  = (int*)alloc((size_t)N_EDGES * 4);

  const size_t msg_bytes = (size_t)N_EDGES * DD * 2;  // 82 MB each
  const size_t base_used = (size_t)(p - (char*)d_ws);
  const bool msg_mode = ws_size >= base_used + 2 * msg_bytes + 512;

  __hip_bfloat16* msg_p = nullptr;
  __hip_bfloat16* msg_s = nullptr;
  float* agg_p = nullptr;
  float* agg_s = nullptr;
  if (msg_mode) {
    msg_p = (__hip_bfloat16*)alloc(msg_bytes);
    msg_s = (__hip_bfloat16*)alloc(msg_bytes);
  } else {
    agg_p = (float*)alloc((size_t)N_NODES * DD * 4);
    agg_s = (float*)alloc((size_t)N_NODES * DD * 4);
  }

  hipMemsetAsync(csr_zero, 0, 4 * (size_t)N_NODES * 4, stream);
  if (!msg_mode)
    hipMemsetAsync(agg_p, 0, 2 * (size_t)N_NODES * DD * 4, stream);

  // weight prep
  wtrans_kernel<<<(256 * 256 + 255) / 256, 256, 0, stream>>>(Wn, Wn_t, 256);
  wtrans_kernel<<<(256 * 128 + 255) / 256, 256, 0, stream>>>(We, We_t, 128);
  wtrans_kernel<<<(256 * 768 + 255) / 256, 256, 0, stream>>>(Wnt, Wnt_t, 768);
  build_we_kernel<<<(768 * 256 + 255) / 256, 256, 0, stream>>>(Wpa, Wsa, Wet, We_edge);
  build_wn_kernel<<<(1024 * 256 + 255) / 256, 256, 0, stream>>>(Wpa, Wsa, Wet, Wn_node);

  // CSR build
  count_kernel<<<(N_EDGES + 255) / 256, 256, 0, stream>>>(src, dst, cnt_out, cnt_in);
  if (msg_mode) {
    scan_kernel<<<1, 256, 0, stream>>>(cnt_in, offs_in, N_NODES);
    scan_kernel<<<1, 256, 0, stream>>>(cnt_out, offs_out, N_NODES);
    fill_kernel<<<(N_EDGES + 255) / 256, 256, 0, stream>>>(
        src, dst, offs_out, offs_in, cur_out, cur_in, pos_out, pos_in);
  }

  // pretrans GEMMs (f32 A, fused convert; relu; bf16 out)
  {
    dim3 g((N_NODES + 127) / 128, 2);
    gemm_mfma_kernel<true, false, true><<<g, 256, 0, stream>>>(
        x, Wn_t, bn, nullptr, pre_n_bf, N_NODES, 4, 256);
  }
  {
    dim3 g(N_EDGES / 128, 2);
    gemm_mfma_kernel<true, false, true><<<g, 256, 0, stream>>>(
        edge_feat, We_t, be, nullptr, pre_e_bf, N_EDGES, 2, 256);
  }

  // node-side precompute: nodeP[N,1024] = pre_n @ Wn_node^T (no bias/relu)
  {
    dim3 g((N_NODES + 127) / 128, 8);
    gemm_mfma_kernel<false, false, false><<<g, 256, 0, stream>>>(
        pre_n_bf, Wn_node, nullptr, nullptr, nodeP, N_NODES, 4, 1024);
  }

  // factored edge GEMM (K=256)
  if (msg_mode) {
    edge_mfma_kernel<true><<<7504, 256, 0, stream>>>(
        pre_e_bf, We_edge, nodeP, src, dst, pos_in, pos_out, bpa, bsa, bet,
        nullptr, nullptr, msg_p, msg_s, edge_out);
    agg_kernel<<<N_NODES, 128, 0, stream>>>(
        msg_p, msg_s, pre_n_bf, offs_in, offs_out, nodeH);
  } else {
    edge_mfma_kernel<false><<<7504, 256, 0, stream>>>(
        pre_e_bf, We_edge, nodeP, src, dst, nullptr, nullptr, bpa, bsa, bet,
        agg_p, agg_s, nullptr, nullptr, edge_out);
    node_prep_kernel<<<N_NODES, 256, 0, stream>>>(
        agg_p, agg_s, pre_n_bf, cnt_in, cnt_out, nodeH);
  }

  // node transformer GEMM
  {
    dim3 g((N_NODES + 127) / 128, 2);
    gemm_mfma_kernel<false, true, false><<<g, 256, 0, stream>>>(
        nodeH, Wnt_t, bnt, node_out, nullptr, N_NODES, 12, 256);
  }
}

// Round 7
// 445.940 us; speedup vs baseline: 1.1759x; 1.1759x over previous
//
#include <hip/hip_runtime.h>
#include <hip/hip_bf16.h>

#define N_NODES 10000
#define N_EDGES 160000
#define DD      256   // hidden dim

typedef __bf16 bf16x8 __attribute__((ext_vector_type(8)));
typedef float  f32x4  __attribute__((ext_vector_type(4)));

// ---------------------------------------------------------------------------
// Fused weight prep: all five bf16 weight layouts in one launch.
//  [0]      Wn_t   [256 n][256 k]  = Wn^T
//  [65536]  We_t   [256 n][128 k]  = We^T
//  [98304]  Wnt_t  [256 n][768 k]  = Wnt^T
//  [294912] We_edge[768 n][256 k]  = pre_e rows of Wpa/Wsa/Wet
//  [491520] Wn_node[1024 n][256 k] = node rows: Wpa0|Wsa0|Wet0|Wet2
// total 753664 elems
// ---------------------------------------------------------------------------
__global__ void prep_weights_kernel(
    const float* __restrict__ Wn, const float* __restrict__ We,
    const float* __restrict__ Wnt, const float* __restrict__ Wpa,
    const float* __restrict__ Wsa, const float* __restrict__ Wet,
    __hip_bfloat16* __restrict__ Wn_t, __hip_bfloat16* __restrict__ We_t,
    __hip_bfloat16* __restrict__ Wnt_t, __hip_bfloat16* __restrict__ We_edge,
    __hip_bfloat16* __restrict__ Wn_node) {
  int idx = blockIdx.x * 256 + threadIdx.x;
  if (idx < 65536) {  // Wn_t
    const int n = idx >> 8, k = idx & 255;
    Wn_t[idx] = __float2bfloat16(Wn[k * 256 + n]);
    return;
  }
  idx -= 65536;
  if (idx < 32768) {  // We_t [256][128]
    const int n = idx >> 7, k = idx & 127;
    We_t[idx] = __float2bfloat16(We[k * 256 + n]);
    return;
  }
  idx -= 32768;
  if (idx < 196608) {  // Wnt_t [256][768]
    const int n = idx / 768, k = idx % 768;
    Wnt_t[idx] = __float2bfloat16(Wnt[k * 256 + n]);
    return;
  }
  idx -= 196608;
  if (idx < 196608) {  // We_edge [768][256]
    const int n = idx >> 8, k = idx & 255;
    float v;
    if (n < 256)      v = Wpa[(256 + k) * 256 + n];
    else if (n < 512) v = Wsa[(256 + k) * 256 + (n - 256)];
    else              v = Wet[(256 + k) * 256 + (n - 512)];
    We_edge[idx] = __float2bfloat16(v);
    return;
  }
  idx -= 196608;
  if (idx < 262144) {  // Wn_node [1024][256]
    const int n = idx >> 8, k = idx & 255;
    float v;
    if (n < 256)      v = Wpa[k * 256 + n];
    else if (n < 512) v = Wsa[k * 256 + (n - 256)];
    else if (n < 768) v = Wet[k * 256 + (n - 512)];
    else              v = Wet[(512 + k) * 256 + (n - 768)];
    Wn_node[idx] = __float2bfloat16(v);
  }
}

// ---------------------------------------------------------------------------
// CSR build: counts, exclusive scans (both in one launch), inverse-perm fill
// ---------------------------------------------------------------------------
__global__ void count_kernel(const int* __restrict__ src, const int* __restrict__ dst,
                             int* __restrict__ cnt_out, int* __restrict__ cnt_in) {
  const int e = blockIdx.x * 256 + threadIdx.x;
  if (e < N_EDGES) {
    atomicAdd(&cnt_out[src[e]], 1);
    atomicAdd(&cnt_in[dst[e]], 1);
  }
}

__global__ __launch_bounds__(256) void scan2_kernel(
    const int* __restrict__ cnt_in, const int* __restrict__ cnt_out,
    int* __restrict__ offs_in, int* __restrict__ offs_out) {
  const int* cnt = blockIdx.x ? cnt_out : cnt_in;
  int* offs      = blockIdx.x ? offs_out : offs_in;
  const int n = N_NODES;
  __shared__ int part[256];
  const int t  = threadIdx.x;
  const int lo = t * 40;
  const int hi = (lo + 40 < n) ? lo + 40 : n;
  int s = 0;
  for (int i = lo; i < hi; ++i) s += cnt[i];
  part[t] = s;
  __syncthreads();
  for (int off = 1; off < 256; off <<= 1) {
    int v = (t >= off) ? part[t - off] : 0;
    __syncthreads();
    part[t] += v;
    __syncthreads();
  }
  int run = (t == 0) ? 0 : part[t - 1];
  for (int i = lo; i < hi; ++i) { offs[i] = run; run += cnt[i]; }
  if (t == 255) offs[n] = run;
}

__global__ void fill_kernel(const int* __restrict__ src, const int* __restrict__ dst,
                            const int* __restrict__ offs_out, const int* __restrict__ offs_in,
                            int* __restrict__ cur_out, int* __restrict__ cur_in,
                            int* __restrict__ pos_out, int* __restrict__ pos_in) {
  const int e = blockIdx.x * 256 + threadIdx.x;
  if (e < N_EDGES) {
    const int u = src[e];
    pos_out[e] = offs_out[u] + atomicAdd(&cur_out[u], 1);
    const int v = dst[e];
    pos_in[e] = offs_in[v] + atomicAdd(&cur_in[v], 1);
  }
}

// ---------------------------------------------------------------------------
// Generic MFMA GEMM, 8-wave / 512-thread blocks (16 waves/CU at 2 blocks).
// out[M,ldo] cols [nt*128..) = act(A[M,K] @ Wt^T + bias).
// Wave tile 32x64 (wave grid 4x2). A_F32: f32 A converted during staging.
// ---------------------------------------------------------------------------
template <bool RELU, bool F32OUT, bool A_F32>
__global__ __launch_bounds__(512, 4) void gemm_mfma_kernel(
    const void* __restrict__ Av, const __hip_bfloat16* __restrict__ Wt,
    const float* __restrict__ bias, float* __restrict__ outf,
    __hip_bfloat16* __restrict__ outb, int M, int Ksteps, int ldo) {
  __shared__ char sA[2][16384];
  __shared__ char sW[2][16384];

  const int K    = Ksteps * 64;
  const int row0 = blockIdx.x * 128;
  const int nt   = blockIdx.y;

  const int tid  = threadIdx.x;
  const int lane = tid & 63;
  const int w    = tid >> 6;   // 0..7

  const int rsub  = lane >> 3;
  const int pslot = lane & 7;
  const int sslot = pslot ^ rsub;

  auto stage = [&](int b, int c) {
#pragma unroll
    for (int j = 0; j < 2; ++j) {
      const int r = w * 16 + j * 8 + rsub;   // 0..127
      int ar = row0 + r;
      if (ar >= M) ar = M - 1;
      if constexpr (A_F32) {
        const float* gp = (const float*)Av + (size_t)ar * K + c * 64 + sslot * 8;
        const f32x4 lo = *(const f32x4*)gp;
        const f32x4 hi = *(const f32x4*)(gp + 4);
        union { __hip_bfloat16 h[8]; bf16x8 v; } pk;
#pragma unroll
        for (int q = 0; q < 4; ++q) pk.h[q] = __float2bfloat16(lo[q]);
#pragma unroll
        for (int q = 0; q < 4; ++q) pk.h[4 + q] = __float2bfloat16(hi[q]);
        *(bf16x8*)&sA[b][r * 128 + pslot * 16] = pk.v;
      } else {
        const __hip_bfloat16* gp =
            (const __hip_bfloat16*)Av + (size_t)ar * K + c * 64 + sslot * 8;
        __builtin_amdgcn_global_load_lds(
            (const __attribute__((address_space(1))) void*)gp,
            (__attribute__((address_space(3))) void*)&sA[b][(w * 16 + j * 8) * 128],
            16, 0, 0);
      }
      const __hip_bfloat16* wp = Wt + (size_t)(nt * 128 + r) * K + c * 64 + sslot * 8;
      __builtin_amdgcn_global_load_lds(
          (const __attribute__((address_space(1))) void*)wp,
          (__attribute__((address_space(3))) void*)&sW[b][(w * 16 + j * 8) * 128],
          16, 0, 0);
    }
  };

  const int wm = (w >> 1) * 32;   // 0,32,64,96
  const int wn = (w & 1) * 64;    // 0,64

  f32x4 acc[2][4];
#pragma unroll
  for (int i = 0; i < 2; ++i)
#pragma unroll
    for (int j = 0; j < 4; ++j) acc[i][j] = (f32x4)0.f;

  stage(0, 0);
  asm volatile("s_waitcnt vmcnt(0)");
  __syncthreads();

  int buf = 0;
  for (int c = 0; c < Ksteps; ++c) {
    if (c + 1 < Ksteps) stage(buf ^ 1, c + 1);
#pragma unroll
    for (int kk = 0; kk < 2; ++kk) {
      bf16x8 av[2], bv[4];
#pragma unroll
      for (int i = 0; i < 2; ++i) {
        const int row  = wm + i * 16 + (lane & 15);
        const int boff = row * 128 + ((kk * 64 + (lane >> 4) * 16) ^ ((row & 7) << 4));
        av[i] = *(const bf16x8*)&sA[buf][boff];
      }
#pragma unroll
      for (int j = 0; j < 4; ++j) {
        const int nrow = wn + j * 16 + (lane & 15);
        const int boff = nrow * 128 + ((kk * 64 + (lane >> 4) * 16) ^ ((nrow & 7) << 4));
        bv[j] = *(const bf16x8*)&sW[buf][boff];
      }
#pragma unroll
      for (int i = 0; i < 2; ++i)
#pragma unroll
        for (int j = 0; j < 4; ++j)
          acc[i][j] = __builtin_amdgcn_mfma_f32_16x16x32_bf16(av[i], bv[j], acc[i][j], 0, 0, 0);
    }
    __syncthreads();
    buf ^= 1;
  }

#pragma unroll
  for (int i = 0; i < 2; ++i) {
    const int row = row0 + wm + i * 16 + ((lane >> 4) << 2);
#pragma unroll
    for (int j = 0; j < 4; ++j) {
      const int col = nt * 128 + wn + j * 16 + (lane & 15);
      const float bb = bias ? bias[col] : 0.f;
#pragma unroll
      for (int r = 0; r < 4; ++r) {
        if (row + r < M) {
          float v = acc[i][j][r] + bb;
          if (RELU) v = v > 0.f ? v : 0.f;
          if (F32OUT) outf[(size_t)(row + r) * ldo + col] = v;
          else        outb[(size_t)(row + r) * ldo + col] = __float2bfloat16(v);
        }
      }
    }
  }
}

// ---------------------------------------------------------------------------
// Factored MFMA edge GEMM, 8-wave blocks: acc = pre_e[128] @ We'[768,256]^T.
// Epilogue adds gathered nodeP rows, bias, relu, scatters msg rows CSR-ordered
// (MSG) or atomicAdds (fallback). XCD-grouped remap keeps an edge-tile's 6
// nt-blocks on one XCD.
// ---------------------------------------------------------------------------
template <bool MSG>
__global__ __launch_bounds__(512, 4) void edge_mfma_kernel(
    const __hip_bfloat16* __restrict__ pre_e,
    const __hip_bfloat16* __restrict__ We,
    const __hip_bfloat16* __restrict__ nodeP,
    const int* __restrict__ src, const int* __restrict__ dst,
    const int* __restrict__ pos_in, const int* __restrict__ pos_out,
    const float* __restrict__ bpa, const float* __restrict__ bsa,
    const float* __restrict__ bet,
    float* __restrict__ agg_p, float* __restrict__ agg_s,
    __hip_bfloat16* __restrict__ msg_p, __hip_bfloat16* __restrict__ msg_s,
    float* __restrict__ edge_out) {
  __shared__ char sA[2][16384];
  __shared__ char sW[2][16384];
  __shared__ int sSrc[128], sDst[128], sPin[128], sPout[128];

  const int bid = blockIdx.x;
  const int xcd = bid & 7;
  const int s   = xcd * 938 + (bid >> 3);
  const int et  = s / 6;
  const int nt  = s % 6;
  if (et >= N_EDGES / 128) return;
  const int mat = nt >> 1;  // 0=P, 1=S, 2=E
  const int e0  = et * 128;

  const int tid  = threadIdx.x;
  const int lane = tid & 63;
  const int w    = tid >> 6;

  if (tid < 128) {
    sSrc[tid] = src[e0 + tid];
    if (MSG) sPin[tid] = pos_in[e0 + tid];
  } else if (tid < 256) {
    sDst[tid - 128] = dst[e0 + tid - 128];
    if (MSG) sPout[tid - 128] = pos_out[e0 + tid - 128];
  }
  __syncthreads();

  const int rsub  = lane >> 3;
  const int pslot = lane & 7;
  const int sslot = pslot ^ rsub;

  auto stage = [&](int b, int c) {
#pragma unroll
    for (int j = 0; j < 2; ++j) {
      const int r = w * 16 + j * 8 + rsub;
      const __hip_bfloat16* gp = pre_e + (size_t)(e0 + r) * 256 + c * 64 + sslot * 8;
      __builtin_amdgcn_global_load_lds(
          (const __attribute__((address_space(1))) void*)gp,
          (__attribute__((address_space(3))) void*)&sA[b][(w * 16 + j * 8) * 128],
          16, 0, 0);
      const __hip_bfloat16* wp = We + (size_t)(nt * 128 + r) * 256 + c * 64 + sslot * 8;
      __builtin_amdgcn_global_load_lds(
          (const __attribute__((address_space(1))) void*)wp,
          (__attribute__((address_space(3))) void*)&sW[b][(w * 16 + j * 8) * 128],
          16, 0, 0);
    }
  };

  const int wm = (w >> 1) * 32;
  const int wn = (w & 1) * 64;

  f32x4 acc[2][4];
#pragma unroll
  for (int i = 0; i < 2; ++i)
#pragma unroll
    for (int j = 0; j < 4; ++j) acc[i][j] = (f32x4)0.f;

  stage(0, 0);
  asm volatile("s_waitcnt vmcnt(0)");
  __syncthreads();

  int buf = 0;
  for (int c = 0; c < 4; ++c) {
    if (c + 1 < 4) stage(buf ^ 1, c + 1);
#pragma unroll
    for (int kk = 0; kk < 2; ++kk) {
      bf16x8 av[2], bv[4];
#pragma unroll
      for (int i = 0; i < 2; ++i) {
        const int row  = wm + i * 16 + (lane & 15);
        const int boff = row * 128 + ((kk * 64 + (lane >> 4) * 16) ^ ((row & 7) << 4));
        av[i] = *(const bf16x8*)&sA[buf][boff];
      }
#pragma unroll
      for (int j = 0; j < 4; ++j) {
        const int nrow = wn + j * 16 + (lane & 15);
        const int boff = nrow * 128 + ((kk * 64 + (lane >> 4) * 16) ^ ((nrow & 7) << 4));
        bv[j] = *(const bf16x8*)&sW[buf][boff];
      }
#pragma unroll
      for (int i = 0; i < 2; ++i)
#pragma unroll
        for (int j = 0; j < 4; ++j)
          acc[i][j] = __builtin_amdgcn_mfma_f32_16x16x32_bf16(av[i], bv[j], acc[i][j], 0, 0, 0);
    }
    __syncthreads();
    buf ^= 1;
  }

  const int colbase = (nt & 1) * 128 + wn;
#pragma unroll
  for (int i = 0; i < 2; ++i) {
    const int lrow = wm + i * 16 + ((lane >> 4) << 2);  // 0..127
#pragma unroll
    for (int j = 0; j < 4; ++j) {
      const int col = colbase + j * 16 + (lane & 15);
      if (mat == 0) {
        const float bb = bpa[col];
#pragma unroll
        for (int r = 0; r < 4; ++r) {
          const int le = lrow + r;
          float v = acc[i][j][r] + bb +
                    __bfloat162float(nodeP[(size_t)sSrc[le] * 1024 + col]);
          v = v > 0.f ? v : 0.f;
          if (MSG) msg_p[(size_t)sPin[le] * 256 + col] = __float2bfloat16(v);
          else     atomicAdd(&agg_p[(size_t)sDst[le] * 256 + col], v);
        }
      } else if (mat == 1) {
        const float bb = bsa[col];
#pragma unroll
        for (int r = 0; r < 4; ++r) {
          const int le = lrow + r;
          float v = acc[i][j][r] + bb +
                    __bfloat162float(nodeP[(size_t)sDst[le] * 1024 + 256 + col]);
          v = v > 0.f ? v : 0.f;
          if (MSG) msg_s[(size_t)sPout[le] * 256 + col] = __float2bfloat16(v);
          else     atomicAdd(&agg_s[(size_t)sSrc[le] * 256 + col], v);
        }
      } else {
        const float bb = bet[col];
#pragma unroll
        for (int r = 0; r < 4; ++r) {
          const int le = lrow + r;
          float v = acc[i][j][r] + bb +
                    __bfloat162float(nodeP[(size_t)sSrc[le] * 1024 + 512 + col]) +
                    __bfloat162float(nodeP[(size_t)sDst[le] * 1024 + 768 + col]);
          edge_out[(size_t)(e0 + le) * 256 + col] = v;
        }
      }
    }
  }
}

// ---------------------------------------------------------------------------
// CSR-ordered segment-sum + nodeH assembly (msg rows contiguous per node).
// ---------------------------------------------------------------------------
__global__ __launch_bounds__(128) void agg_kernel(
    const __hip_bfloat16* __restrict__ msg_p, const __hip_bfloat16* __restrict__ msg_s,
    const __hip_bfloat16* __restrict__ pre_n,
    const int* __restrict__ offs_in, const int* __restrict__ offs_out,
    __hip_bfloat16* __restrict__ nodeH) {
  const int v    = blockIdx.x;
  const int wave = threadIdx.x >> 6;
  const int lane = threadIdx.x & 63;
  const int cg   = lane & 31;
  const int par  = lane >> 5;

  const int* offs = wave ? offs_out : offs_in;
  const __hip_bfloat16* msg = wave ? msg_s : msg_p;

  const int p0 = offs[v], p1 = offs[v + 1];
  float acc[8];
#pragma unroll
  for (int k = 0; k < 8; ++k) acc[k] = 0.f;

  for (int i = p0 + par; i < p1; i += 2) {
    const uint4 u = *(const uint4*)(msg + (size_t)i * 256 + cg * 8);
    const unsigned short* h = (const unsigned short*)&u;
#pragma unroll
    for (int k = 0; k < 8; ++k) acc[k] += __uint_as_float((unsigned)h[k] << 16);
  }
#pragma unroll
  for (int k = 0; k < 8; ++k) acc[k] += __shfl_xor(acc[k], 32);

  if (par == 0) {
    const int deg = p1 - p0;
    const float inv = 1.f / (float)(deg > 1 ? deg : 1);
    union { __hip_bfloat16 h[8]; uint4 u; } o;
#pragma unroll
    for (int k = 0; k < 8; ++k) o.h[k] = __float2bfloat16(acc[k] * inv);
    *(uint4*)(nodeH + (size_t)v * 768 + wave * 512 + cg * 8) = o.u;
  } else if (wave == 0) {
    const uint4 u = *(const uint4*)(pre_n + (size_t)v * 256 + cg * 8);
    *(uint4*)(nodeH + (size_t)v * 768 + 256 + cg * 8) = u;
  }
}

// ---------------------------------------------------------------------------
// fallback node prep (atomic path)
// ---------------------------------------------------------------------------
__global__ void node_prep_kernel(const float* __restrict__ agg_p,
                                 const float* __restrict__ agg_s,
                                 const __hip_bfloat16* __restrict__ pre_n,
                                 const int* __restrict__ cnt_in,
                                 const int* __restrict__ cnt_out,
                                 __hip_bfloat16* __restrict__ nodeH) {
  const int row = blockIdx.x;
  const int c   = threadIdx.x;
  const float di = (float)(cnt_in[row]  > 1 ? cnt_in[row]  : 1);
  const float dd = (float)(cnt_out[row] > 1 ? cnt_out[row] : 1);
  nodeH[(size_t)row * 768 + c]       = __float2bfloat16(agg_p[(size_t)row * 256 + c] / di);
  nodeH[(size_t)row * 768 + 256 + c] = pre_n[(size_t)row * 256 + c];
  nodeH[(size_t)row * 768 + 512 + c] = __float2bfloat16(agg_s[(size_t)row * 256 + c] / dd);
}

// ---------------------------------------------------------------------------
extern "C" void kernel_launch(void* const* d_in, const int* in_sizes, int n_in,
                              void* d_out, int out_size, void* d_ws, size_t ws_size,
                              hipStream_t stream) {
  const float* x         = (const float*)d_in[0];
  const float* edge_feat = (const float*)d_in[1];
  const int*   edge_idx  = (const int*)d_in[2];
  const float* Wn  = (const float*)d_in[3];
  const float* bn  = (const float*)d_in[4];
  const float* We  = (const float*)d_in[5];
  const float* be  = (const float*)d_in[6];
  const float* Wpa = (const float*)d_in[7];
  const float* bpa = (const float*)d_in[8];
  const float* Wsa = (const float*)d_in[9];
  const float* bsa = (const float*)d_in[10];
  const float* Wnt = (const float*)d_in[11];
  const float* bnt = (const float*)d_in[12];
  const float* Wet = (const float*)d_in[13];
  const float* bet = (const float*)d_in[14];

  const int* src = edge_idx;
  const int* dst = edge_idx + N_EDGES;

  float* node_out = (float*)d_out;
  float* edge_out = (float*)d_out + (size_t)N_NODES * DD;

  char* p = (char*)d_ws;
  auto alloc = [&](size_t bytes) -> void* {
    void* r = (void*)p;
    p += (bytes + 255) & ~(size_t)255;
    return r;
  };

  __hip_bfloat16* pre_n_bf = (__hip_bfloat16*)alloc((size_t)N_NODES * DD * 2);
  __hip_bfloat16* pre_e_bf = (__hip_bfloat16*)alloc((size_t)N_EDGES * DD * 2);
  __hip_bfloat16* nodeH    = (__hip_bfloat16*)alloc((size_t)N_NODES * 768 * 2);
  __hip_bfloat16* nodeP    = (__hip_bfloat16*)alloc((size_t)N_NODES * 1024 * 2);
  __hip_bfloat16* We_edge  = (__hip_bfloat16*)alloc((size_t)768 * 256 * 2);
  __hip_bfloat16* Wn_node  = (__hip_bfloat16*)alloc((size_t)1024 * 256 * 2);
  __hip_bfloat16* Wn_t     = (__hip_bfloat16*)alloc((size_t)256 * 256 * 2);
  __hip_bfloat16* We_t     = (__hip_bfloat16*)alloc((size_t)256 * 128 * 2);
  __hip_bfloat16* Wnt_t    = (__hip_bfloat16*)alloc((size_t)256 * 768 * 2);
  int* csr_zero = (int*)alloc(4 * (size_t)N_NODES * 4);  // cnt_in|cnt_out|cur_in|cur_out
  int* cnt_in   = csr_zero;
  int* cnt_out  = csr_zero + N_NODES;
  int* cur_in   = csr_zero + 2 * N_NODES;
  int* cur_out  = csr_zero + 3 * N_NODES;
  int* offs_in  = (int*)alloc(((size_t)N_NODES + 1) * 4);
  int* offs_out = (int*)alloc(((size_t)N_NODES + 1) * 4);
  int* pos_in   = (int*)alloc((size_t)N_EDGES * 4);
  int* pos_out  = (int*)alloc((size_t)N_EDGES * 4);

  const size_t msg_bytes = (size_t)N_EDGES * DD * 2;  // 82 MB each
  const size_t base_used = (size_t)(p - (char*)d_ws);
  const bool msg_mode = ws_size >= base_used + 2 * msg_bytes + 512;

  __hip_bfloat16* msg_p = nullptr;
  __hip_bfloat16* msg_s = nullptr;
  float* agg_p = nullptr;
  float* agg_s = nullptr;
  if (msg_mode) {
    msg_p = (__hip_bfloat16*)alloc(msg_bytes);
    msg_s = (__hip_bfloat16*)alloc(msg_bytes);
  } else {
    agg_p = (float*)alloc((size_t)N_NODES * DD * 4);
    agg_s = (float*)alloc((size_t)N_NODES * DD * 4);
  }

  hipMemsetAsync(csr_zero, 0, 4 * (size_t)N_NODES * 4, stream);
  if (!msg_mode)
    hipMemsetAsync(agg_p, 0, 2 * (size_t)N_NODES * DD * 4, stream);

  prep_weights_kernel<<<(753664 + 255) / 256, 256, 0, stream>>>(
      Wn, We, Wnt, Wpa, Wsa, Wet, Wn_t, We_t, Wnt_t, We_edge, Wn_node);

  count_kernel<<<(N_EDGES + 255) / 256, 256, 0, stream>>>(src, dst, cnt_out, cnt_in);
  if (msg_mode) {
    scan2_kernel<<<2, 256, 0, stream>>>(cnt_in, cnt_out, offs_in, offs_out);
    fill_kernel<<<(N_EDGES + 255) / 256, 256, 0, stream>>>(
        src, dst, offs_out, offs_in, cur_out, cur_in, pos_out, pos_in);
  }

  // pretrans GEMMs (f32 A, fused convert; relu; bf16 out)
  {
    dim3 g((N_NODES + 127) / 128, 2);
    gemm_mfma_kernel<true, false, true><<<g, 512, 0, stream>>>(
        x, Wn_t, bn, nullptr, pre_n_bf, N_NODES, 4, 256);
  }
  {
    dim3 g(N_EDGES / 128, 2);
    gemm_mfma_kernel<true, false, true><<<g, 512, 0, stream>>>(
        edge_feat, We_t, be, nullptr, pre_e_bf, N_EDGES, 2, 256);
  }

  // node-side precompute: nodeP[N,1024] = pre_n @ Wn_node^T
  {
    dim3 g((N_NODES + 127) / 128, 8);
    gemm_mfma_kernel<false, false, false><<<g, 512, 0, stream>>>(
        pre_n_bf, Wn_node, nullptr, nullptr, nodeP, N_NODES, 4, 1024);
  }

  // factored edge GEMM (K=256)
  if (msg_mode) {
    edge_mfma_kernel<true><<<7504, 512, 0, stream>>>(
        pre_e_bf, We_edge, nodeP, src, dst, pos_in, pos_out, bpa, bsa, bet,
        nullptr, nullptr, msg_p, msg_s, edge_out);
    agg_kernel<<<N_NODES, 128, 0, stream>>>(
        msg_p, msg_s, pre_n_bf, offs_in, offs_out, nodeH);
  } else {
    edge_mfma_kernel<false><<<7504, 512, 0, stream>>>(
        pre_e_bf, We_edge, nodeP, src, dst, nullptr, nullptr, bpa, bsa, bet,
        agg_p, agg_s, nullptr, nullptr, edge_out);
    node_prep_kernel<<<N_NODES, 256, 0, stream>>>(
        agg_p, agg_s, pre_n_bf, cnt_in, cnt_out, nodeH);
  }

  // node transformer GEMM
  {
    dim3 g((N_NODES + 127) / 128, 2);
    gemm_mfma_kernel<false, true, false><<<g, 512, 0, stream>>>(
        nodeH, Wnt_t, bnt, node_out, nullptr, N_NODES, 12, 256);
  }
}